// Round 7
// baseline (3566.789 us; speedup 1.0000x reference)
//
#include <hip/hip_runtime.h>
#include <hip/hip_bf16.h>
#include <hip/hip_fp16.h>
#include <math.h>

#define Q_N 4096
#define M_N 65536
#define D_N 1024
#define TOPK 8
#define SEGS 32
#define KPS (M_N / SEGS)       // 2048 keys per segment
#define CANDS (SEGS * TOPK)    // 256 candidates per query
#define NRES 32                // rescored candidates per query

// MFMA tile params
#define BMQ 256                // queries per block (8 waves x 32)
#define BNK 128                // keys per step tile
#define BK 32
#define NSUB (KPS / BNK)       // 16 subtiles per segment
#define NKT (D_N / BK)         // 32 K-steps per subtile
#define NSTEP (NSUB * NKT)     // 512 pipeline steps per block (one segment)
#define QTILES (Q_N / BMQ)     // 16

typedef short s16x8 __attribute__((ext_vector_type(8)));
typedef float f32x16 __attribute__((ext_vector_type(16)));

__device__ __forceinline__ bool better(float v0, int i0, float v1, int i1) {
  return (v0 > v1) || (v0 == v1 && i0 < i1);
}

__device__ __forceinline__ unsigned short f2bf(float f) {
  union { __hip_bfloat16 h; unsigned short u; } c;
  c.h = __float2bfloat16(f);
  return c.u;
}

// async global->LDS, 16B per lane; lds base wave-uniform, dest linear (lane*16)
__device__ __forceinline__ void gll16(void* lds, const void* g) {
  __builtin_amdgcn_global_load_lds(
      (const __attribute__((address_space(1))) unsigned int*)(uintptr_t)g,
      (__attribute__((address_space(3))) unsigned int*)(uintptr_t)lds, 16, 0, 0);
}

// ---------------- K1: key norms + normalized bf16 conversion ----------------
__global__ __launch_bounds__(256) void knorm_scale_kernel(const float* __restrict__ keys,
                                                          unsigned short* __restrict__ kb,
                                                          float* __restrict__ rnk) {
  int row = blockIdx.x;
  int tid = threadIdx.x;
  float4 v = reinterpret_cast<const float4*>(keys + (size_t)row * D_N)[tid];
  float s = v.x * v.x + v.y * v.y + v.z * v.z + v.w * v.w;
#pragma unroll
  for (int off = 32; off > 0; off >>= 1) s += __shfl_down(s, off);
  __shared__ float part[4];
  __shared__ float rs;
  int lane = tid & 63, wid = tid >> 6;
  if (lane == 0) part[wid] = s;
  __syncthreads();
  if (tid == 0) {
    float t = part[0] + part[1] + part[2] + part[3];
    rs = 1.0f / fmaxf(sqrtf(t), 1e-12f);
  }
  __syncthreads();
  float r = rs;
  ushort4 o;
  o.x = f2bf(v.x * r); o.y = f2bf(v.y * r); o.z = f2bf(v.z * r); o.w = f2bf(v.w * r);
  reinterpret_cast<ushort4*>(kb + (size_t)row * D_N)[tid] = o;
  if (tid == 0) rnk[row] = r;
}

// ---------------- K2: query norms -> fp32 (rescore) + bf16 (MFMA) ----------
__global__ __launch_bounds__(256) void qnorm_dual_kernel(const float* __restrict__ q,
                                                         float* __restrict__ qn,
                                                         unsigned short* __restrict__ qb) {
  int row = blockIdx.x;
  int tid = threadIdx.x;
  float4 v = reinterpret_cast<const float4*>(q + (size_t)row * D_N)[tid];
  float s = v.x * v.x + v.y * v.y + v.z * v.z + v.w * v.w;
#pragma unroll
  for (int off = 32; off > 0; off >>= 1) s += __shfl_down(s, off);
  __shared__ float part[4];
  __shared__ float rs;
  int lane = tid & 63, wid = tid >> 6;
  if (lane == 0) part[wid] = s;
  __syncthreads();
  if (tid == 0) {
    float t = part[0] + part[1] + part[2] + part[3];
    rs = 1.0f / fmaxf(sqrtf(t), 1e-12f);
  }
  __syncthreads();
  float r = rs;
  float4 o;
  o.x = v.x * r; o.y = v.y * r; o.z = v.z * r; o.w = v.w * r;
  reinterpret_cast<float4*>(qn + (size_t)row * D_N)[tid] = o;
  ushort4 ob;
  ob.x = f2bf(o.x); ob.y = f2bf(o.y); ob.z = f2bf(o.z); ob.w = f2bf(o.w);
  reinterpret_cast<ushort4*>(qb + (size_t)row * D_N)[tid] = ob;
}

// ---------------- K3: bf16 MFMA sims + in-register per-segment top-8 --------
// grid = 512 (2 blocks/CU), block = 512 threads (8 waves). Block = 256 queries
// x one segment (2048 keys). Wave = 32 queries x 128 keys using 32x32x16 MFMA
// with SWAPPED operands: mfma(keyfrag, queryfrag) -> D[key][query]; lane holds
// 1 query x 32 keys per subtile -> top-8 fully in registers. Depth-2
// counted-vmcnt pipeline (vmcnt(3), never drained mid-loop), raw s_barriers.
__global__ __launch_bounds__(512, 4) void simsb_kernel(const unsigned short* __restrict__ qb,
                                                       const unsigned short* __restrict__ kb,
                                                       float* __restrict__ cand_val,
                                                       int* __restrict__ cand_idx) {
  __shared__ __align__(16) union SmemU {
    struct {
      unsigned short A[2][BMQ * BK];  // 2 x 16 KB queries
      unsigned short B[2][BNK * BK];  // 2 x 8 KB keys
    } ab;                             // 48 KB
    struct {
      float v[BMQ * 2 * TOPK];        // 16 KB: per-query 2 partition lists
      int i[BMQ * 2 * TOPK];          // 16 KB
    } mg;
  } smem;

  const int tid = threadIdx.x;
  const int lane = tid & 63;
  const int wid = tid >> 6;          // 0..7

  // mapping: xcd = orig&7 (round-robin dispatch); s = orig>>3: qtile = s&15,
  // segslot = s>>4 (0..3); seg = xcd*4 + segslot. All 512 blocks co-resident.
  const int orig = blockIdx.x;
  const int s = orig >> 3;
  const int qtile = s & 15;
  const int seg = ((orig & 7) << 2) + (s >> 4);
  const int qbase = qtile * BMQ;
  const int segBase = seg * KPS;

  // staging geometry (involutive chunk swizzle on global source, LDS linear):
  // A: wave stages rows [wid*32, +32) (2 gll16); B: rows [wid*16, +16) (1)
  const int srowA = (wid << 5) + (lane >> 2);
  const int srowB = (wid << 4) + (lane >> 2);
  const int scol = (((lane & 3) ^ ((lane >> 3) & 3)) << 3);
  const unsigned short* aSrc = qb + (size_t)(qbase + srowA) * D_N + scol;
  const unsigned short* bSrc = kb + (size_t)(segBase + srowB) * D_N + scol;

  // fragment geometry (32x32x16): lane holds row/col r31 = lane&31,
  // k = kh*16 + hi*8 -> chunk c = kh*2+hi, phys = c ^ ((r31>>1)&3)
  const int r31 = lane & 31;
  const int hi = lane >> 5;
  const int xorv = (r31 >> 1) & 3;
  int aOff[2], bOff[2];
#pragma unroll
  for (int kh = 0; kh < 2; ++kh) {
    const int phys = ((kh << 1) + hi) ^ xorv;
    bOff[kh] = (r31 << 5) + (phys << 3);                     // + kg*1024 elems
    aOff[kh] = (((wid << 5) + r31) << 5) + (phys << 3);      // query row
  }

  // per-lane running top-8 for query (qbase + wid*32 + r31), key partition hi
  float lv[TOPK];
  int li[TOPK];
#pragma unroll
  for (int j = 0; j < TOPK; ++j) { lv[j] = -1e30f; li[j] = 0x7fffffff; }

  f32x16 acc[4];
#pragma unroll
  for (int kg = 0; kg < 4; ++kg) acc[kg] = (f32x16)0.0f;

  // prologue: stage steps 0,1 (3 gll16/wave each -> 6 outstanding)
#pragma unroll
  for (int p = 0; p < 2; ++p) {
    gll16(smem.ab.A[p] + (wid << 10), aSrc + (p << 5));
    gll16(smem.ab.A[p] + (wid << 10) + 512, aSrc + (size_t)16 * D_N + (p << 5));
    gll16(smem.ab.B[p] + (wid << 9), bSrc + (p << 5));
  }

#pragma unroll 1
  for (int v = 0; v < NSTEP; ++v) {
    if (v < NSTEP - 1) {
      asm volatile("s_waitcnt vmcnt(3)" ::: "memory");   // own step done, next in flight
    } else {
      asm volatile("s_waitcnt vmcnt(0)" ::: "memory");
    }
    __builtin_amdgcn_sched_barrier(0);
    __builtin_amdgcn_s_barrier();
    __builtin_amdgcn_sched_barrier(0);

    const unsigned short* Ab = smem.ab.A[v & 1];
    const unsigned short* Bb = smem.ab.B[v & 1];
    s16x8 af[4][2], bq[2];
#pragma unroll
    for (int kg = 0; kg < 4; ++kg)
#pragma unroll
      for (int kh = 0; kh < 2; ++kh)
        af[kg][kh] = *(const s16x8*)(Bb + bOff[kh] + (kg << 10));
#pragma unroll
    for (int kh = 0; kh < 2; ++kh) bq[kh] = *(const s16x8*)(Ab + aOff[kh]);
    asm volatile("s_waitcnt lgkmcnt(0)" ::: "memory");
    __builtin_amdgcn_sched_barrier(0);
    __builtin_amdgcn_s_barrier();   // all waves' frag reads done
    __builtin_amdgcn_sched_barrier(0);

    // restage just-read buffer with step v+2 (stays in flight across barriers)
    if (v + 2 < NSTEP) {
      const int v2 = v + 2;
      const unsigned short* aS = aSrc + ((v2 & 31) << 5);
      const unsigned short* bS = bSrc + (size_t)(v2 >> 5) * (128 * D_N) + ((v2 & 31) << 5);
      gll16(smem.ab.A[v & 1] + (wid << 10), aS);
      gll16(smem.ab.A[v & 1] + (wid << 10) + 512, aS + (size_t)16 * D_N);
      gll16(smem.ab.B[v & 1] + (wid << 9), bS);
    }

#pragma unroll
    for (int kh = 0; kh < 2; ++kh)
#pragma unroll
      for (int kg = 0; kg < 4; ++kg)
        acc[kg] = __builtin_amdgcn_mfma_f32_32x32x16_bf16(af[kg][kh], bq[kh], acc[kg], 0, 0, 0);

    // subtile boundary: fold acc into per-lane top-8, reset acc
    // D layout (32x32): col = lane&31 (query), row = (r&3) + 8*(r>>2) + 4*hi
    if ((v & (NKT - 1)) == NKT - 1) {
      const int kb0 = segBase + ((v >> 5) << 7) + (hi << 2);
#pragma unroll
      for (int kg = 0; kg < 4; ++kg) {
#pragma unroll
        for (int r = 0; r < 16; ++r) {
          float val = acc[kg][r];
          int id = kb0 + (kg << 5) + (r & 3) + ((r >> 2) << 3);
          if (better(val, id, lv[TOPK - 1], li[TOPK - 1])) {
            float cv = val; int ci = id;
#pragma unroll
            for (int p = 0; p < TOPK; ++p) {
              if (better(cv, ci, lv[p], li[p])) {
                float tv = lv[p]; int ti = li[p];
                lv[p] = cv; li[p] = ci;
                cv = tv; ci = ti;
              }
            }
          }
        }
        acc[kg] = (f32x16)0.0f;
      }
    }
  }

  __syncthreads();   // all LDS frag reads done before overlaying mg scratch

  // dump per-lane lists: query-local ql = wid*32 + r31, partition hi
  {
    const int ql = (wid << 5) + r31;
#pragma unroll
    for (int j = 0; j < TOPK; ++j) {
      smem.mg.v[((ql << 1) + hi) * TOPK + j] = lv[j];
      smem.mg.i[((ql << 1) + hi) * TOPK + j] = li[j];
    }
  }
  __syncthreads();

  // thread per query: 2-way merge of the 2 sorted partition lists -> top-8
  if (tid < BMQ) {
    const int rb = tid << 4;   // 2 lists x 8
    int p0 = 0, p1 = 0;
    size_t base = (size_t)(qbase + tid) * CANDS + seg * TOPK;
#pragma unroll
    for (int j = 0; j < TOPK; ++j) {
      float v0 = smem.mg.v[rb + 0 + p0];  int i0 = smem.mg.i[rb + 0 + p0];
      float v1 = smem.mg.v[rb + 8 + p1];  int i1 = smem.mg.i[rb + 8 + p1];
      bool t0 = better(v0, i0, v1, i1);
      cand_val[base + j] = t0 ? v0 : v1;
      cand_idx[base + j] = t0 ? i0 : i1;
      p0 += t0 ? 1 : 0;
      p1 += t0 ? 0 : 1;
    }
  }
}

// ---------------- K4: merge + exact fp32 rescore + select + gather ---------
__global__ __launch_bounds__(256) void merge_kernel(const float* __restrict__ qn,
                                                    const float* __restrict__ keys,
                                                    const float* __restrict__ values,
                                                    const float* __restrict__ rnk,
                                                    const float* __restrict__ cand_val,
                                                    const int* __restrict__ cand_idx,
                                                    float* __restrict__ out) {
  const int q = blockIdx.x;
  const int tid = threadIdx.x;
  const int lane = tid & 63;
  const int w = tid >> 6;
  __shared__ float sv[CANDS];
  __shared__ int si[CANDS];
  sv[tid] = cand_val[(size_t)q * CANDS + tid];
  si[tid] = cand_idx[(size_t)q * CANDS + tid];
  __syncthreads();
  for (int k = 2; k <= CANDS; k <<= 1) {
    for (int j = k >> 1; j > 0; j >>= 1) {
      int ixj = tid ^ j;
      if (ixj > tid) {
        float v0 = sv[tid], v1 = sv[ixj];
        int i0 = si[tid], i1 = si[ixj];
        bool desc = ((tid & k) == 0);
        bool dosw = desc ? better(v1, i1, v0, i0) : better(v0, i0, v1, i1);
        if (dosw) { sv[tid] = v1; si[tid] = i1; sv[ixj] = v0; si[ixj] = i0; }
      }
      __syncthreads();
    }
  }
  __shared__ float rsc[NRES];
  const float* qrow = &qn[(size_t)q * D_N + lane * 16];
  float4 qv0 = *reinterpret_cast<const float4*>(qrow + 0);
  float4 qv1 = *reinterpret_cast<const float4*>(qrow + 4);
  float4 qv2 = *reinterpret_cast<const float4*>(qrow + 8);
  float4 qv3 = *reinterpret_cast<const float4*>(qrow + 12);
  for (int c = w; c < NRES; c += 4) {
    int id = si[c];
    const float* kr = &keys[(size_t)id * D_N + lane * 16];
    float4 k0 = *reinterpret_cast<const float4*>(kr + 0);
    float4 k1 = *reinterpret_cast<const float4*>(kr + 4);
    float4 k2 = *reinterpret_cast<const float4*>(kr + 8);
    float4 k3 = *reinterpret_cast<const float4*>(kr + 12);
    float s = qv0.x * k0.x + qv0.y * k0.y + qv0.z * k0.z + qv0.w * k0.w
            + qv1.x * k1.x + qv1.y * k1.y + qv1.z * k1.z + qv1.w * k1.w
            + qv2.x * k2.x + qv2.y * k2.y + qv2.z * k2.z + qv2.w * k2.w
            + qv3.x * k3.x + qv3.y * k3.y + qv3.z * k3.z + qv3.w * k3.w;
#pragma unroll
    for (int off = 32; off > 0; off >>= 1) s += __shfl_down(s, off);
    if (lane == 0) rsc[c] = s * rnk[id];
  }
  __syncthreads();
  __shared__ int sel[TOPK];
  if (tid == 0) {
    unsigned used = 0;
    for (int j = 0; j < TOPK; ++j) {
      int best = -1;
      for (int c = 0; c < NRES; ++c) {
        if ((used >> c) & 1u) continue;
        if (best < 0 || better(rsc[c], si[c], rsc[best], si[best])) best = c;
      }
      used |= 1u << best;
      sel[j] = si[best];
    }
  }
  __syncthreads();
#pragma unroll
  for (int j = 0; j < TOPK; ++j) {
    int row = sel[j];
    float4 v = *reinterpret_cast<const float4*>(&values[(size_t)row * D_N + tid * 4]);
    *reinterpret_cast<float4*>(&out[(size_t)q * (TOPK * D_N) + j * D_N + tid * 4]) = v;
  }
}

extern "C" void kernel_launch(void* const* d_in, const int* in_sizes, int n_in,
                              void* d_out, int out_size, void* d_ws, size_t ws_size,
                              hipStream_t stream) {
  const float* query  = (const float*)d_in[0];
  const float* keys   = (const float*)d_in[1];
  const float* values = (const float*)d_in[2];
  float* out = (float*)d_out;
  char* ws = (char*)d_ws;

  const size_t offQn  = 0;
  const size_t offQb  = offQn + (size_t)Q_N * D_N * 4;
  const size_t offKb  = offQb + (size_t)Q_N * D_N * 2;
  const size_t offRnk = offKb + (size_t)M_N * D_N * 2;
  const size_t offCv  = offRnk + (size_t)M_N * 4;
  const size_t offCi  = offCv + (size_t)Q_N * CANDS * 4;

  float* qn = (float*)(ws + offQn);
  unsigned short* qb = (unsigned short*)(ws + offQb);
  unsigned short* kb = (unsigned short*)(ws + offKb);
  float* rnk = (float*)(ws + offRnk);
  float* cand_val = (float*)(ws + offCv);
  int* cand_idx = (int*)(ws + offCi);

  hipLaunchKernelGGL(knorm_scale_kernel, dim3(M_N), dim3(256), 0, stream, keys, kb, rnk);
  hipLaunchKernelGGL(qnorm_dual_kernel, dim3(Q_N), dim3(256), 0, stream, query, qn, qb);
  hipLaunchKernelGGL(simsb_kernel, dim3(QTILES * SEGS), dim3(512), 0, stream,
                     qb, kb, cand_val, cand_idx);
  hipLaunchKernelGGL(merge_kernel, dim3(Q_N), dim3(256), 0, stream,
                     qn, keys, values, rnk, cand_val, cand_idx, out);
}

// Round 8
// 1564.572 us; speedup vs baseline: 2.2797x; 2.2797x over previous
//
#include <hip/hip_runtime.h>
#include <hip/hip_bf16.h>
#include <hip/hip_fp16.h>
#include <math.h>

#define Q_N 4096
#define M_N 65536
#define D_N 1024
#define TOPK 8
#define SEGS 32
#define KPS (M_N / SEGS)       // 2048 keys per segment
#define CANDS (SEGS * TOPK)    // 256 candidates per query
#define NRES 32                // rescored candidates per query

// MFMA tile params (R5-validated skeleton)
#define BM 128                 // queries per block
#define BN 128                 // keys per step tile
#define BK 32
#define NSUB (KPS / BN)        // 16 subtiles per segment
#define NKT (D_N / BK)         // 32 K-steps per subtile
#define NSTEP (NSUB * NKT)     // 512 pipeline steps per segment
#define QT128 (Q_N / BM)       // 32 query tiles

typedef short s16x8 __attribute__((ext_vector_type(8)));
typedef float f32x4 __attribute__((ext_vector_type(4)));

__device__ __forceinline__ bool better(float v0, int i0, float v1, int i1) {
  return (v0 > v1) || (v0 == v1 && i0 < i1);
}

__device__ __forceinline__ unsigned short f2bf(float f) {
  union { __hip_bfloat16 h; unsigned short u; } c;
  c.h = __float2bfloat16(f);
  return c.u;
}

// async global->LDS, 16B per lane; lds base wave-uniform, dest linear (lane*16)
__device__ __forceinline__ void gll16(void* lds, const void* g) {
  __builtin_amdgcn_global_load_lds(
      (const __attribute__((address_space(1))) unsigned int*)(uintptr_t)g,
      (__attribute__((address_space(3))) unsigned int*)(uintptr_t)lds, 16, 0, 0);
}

// ---------------- K1: key norms + normalized bf16 conversion ----------------
__global__ __launch_bounds__(256) void knorm_scale_kernel(const float* __restrict__ keys,
                                                          unsigned short* __restrict__ kb,
                                                          float* __restrict__ rnk) {
  int row = blockIdx.x;
  int tid = threadIdx.x;
  float4 v = reinterpret_cast<const float4*>(keys + (size_t)row * D_N)[tid];
  float s = v.x * v.x + v.y * v.y + v.z * v.z + v.w * v.w;
#pragma unroll
  for (int off = 32; off > 0; off >>= 1) s += __shfl_down(s, off);
  __shared__ float part[4];
  __shared__ float rs;
  int lane = tid & 63, wid = tid >> 6;
  if (lane == 0) part[wid] = s;
  __syncthreads();
  if (tid == 0) {
    float t = part[0] + part[1] + part[2] + part[3];
    rs = 1.0f / fmaxf(sqrtf(t), 1e-12f);
  }
  __syncthreads();
  float r = rs;
  ushort4 o;
  o.x = f2bf(v.x * r); o.y = f2bf(v.y * r); o.z = f2bf(v.z * r); o.w = f2bf(v.w * r);
  reinterpret_cast<ushort4*>(kb + (size_t)row * D_N)[tid] = o;
  if (tid == 0) rnk[row] = r;
}

// ---------------- K2: query norms -> fp32 (rescore) + bf16 (MFMA) ----------
__global__ __launch_bounds__(256) void qnorm_dual_kernel(const float* __restrict__ q,
                                                         float* __restrict__ qn,
                                                         unsigned short* __restrict__ qb) {
  int row = blockIdx.x;
  int tid = threadIdx.x;
  float4 v = reinterpret_cast<const float4*>(q + (size_t)row * D_N)[tid];
  float s = v.x * v.x + v.y * v.y + v.z * v.z + v.w * v.w;
#pragma unroll
  for (int off = 32; off > 0; off >>= 1) s += __shfl_down(s, off);
  __shared__ float part[4];
  __shared__ float rs;
  int lane = tid & 63, wid = tid >> 6;
  if (lane == 0) part[wid] = s;
  __syncthreads();
  if (tid == 0) {
    float t = part[0] + part[1] + part[2] + part[3];
    rs = 1.0f / fmaxf(sqrtf(t), 1e-12f);
  }
  __syncthreads();
  float r = rs;
  float4 o;
  o.x = v.x * r; o.y = v.y * r; o.z = v.z * r; o.w = v.w * r;
  reinterpret_cast<float4*>(qn + (size_t)row * D_N)[tid] = o;
  ushort4 ob;
  ob.x = f2bf(o.x); ob.y = f2bf(o.y); ob.z = f2bf(o.z); ob.w = f2bf(o.w);
  reinterpret_cast<ushort4*>(qb + (size_t)row * D_N)[tid] = ob;
}

// ---------------- K3: bf16 MFMA sims + in-register per-segment top-8 --------
// R5 skeleton (grid 1024, 256 thr / 4 waves, wave = 32q x 128k, swapped-operand
// 16x16x32 MFMA, depth-2 counted-vmcnt pipeline, raw s_barriers) with the A
// (query) operand moved OUT of LDS: per-lane global->register loads, one-step
// prefetch via ping-pong regs (2-step-unrolled loop; compile-time indices).
// LDS now stages only keys: reads 32KB/step, writes 8KB/step per block.
__global__ __launch_bounds__(256, 3) void simsb_kernel(const unsigned short* __restrict__ qb,
                                                       const unsigned short* __restrict__ kb,
                                                       float* __restrict__ cand_val,
                                                       int* __restrict__ cand_idx) {
  __shared__ __align__(16) union SmemU {
    unsigned short B[2][BN * BK];    // 2 x 8 KB keys
    struct {
      float v[BM * 4 * TOPK];        // 16 KB: per-query 4 lane-group lists
      int i[BM * 4 * TOPK];          // 16 KB
    } mg;
  } smem;

  const int tid = threadIdx.x;
  const int lane = tid & 63;
  const int wid = tid >> 6;

  // round-synchronized mapping (R5): XCD = orig&7, 4 rounds of 32 CU-slots
  const int orig = blockIdx.x;
  const int seg = (orig & 7) * 4 + (orig >> 8);
  const int qtile = (orig >> 3) & 31;
  const int qbase = qtile * BM;
  const int segBase = seg * KPS;

  // B staging geometry: wave wid stages tile rows [wid*32, wid*32+32)
  // involutive chunk swizzle on global source; LDS dest linear
  const int srow = (wid << 5) + (lane >> 2);
  const int scol = (((lane & 3) ^ ((lane >> 3) & 3)) << 3);
  const unsigned short* bSeg = kb + (size_t)(segBase + srow) * D_N + scol;

  // fragment geometry: fr = row-within-16, g = k-chunk group
  const int fr = lane & 15;
  const int g = lane >> 4;
  const int chunk_phys = g ^ ((fr >> 1) & 3);
  const int bBase = (fr << 5) + (chunk_phys << 3);   // keys tile read base

  // A (query) operand direct-from-global: lane reads rows
  // qbase + wid*32 + n*16 + fr, k-elems kt*32 + g*8 (natural layout, no swizzle)
  const unsigned short* aReg0 = qb + (size_t)(qbase + (wid << 5) + fr) * D_N + (g << 3);
  const unsigned short* aReg1 = aReg0 + (size_t)16 * D_N;

  // per-lane running top-8 for 2 queries over this lane's key partition
  float lv[2][TOPK];
  int li[2][TOPK];
#pragma unroll
  for (int n = 0; n < 2; ++n)
#pragma unroll
    for (int j = 0; j < TOPK; ++j) { lv[n][j] = -1e30f; li[n][j] = 0x7fffffff; }

  f32x4 acc[8][2];
#pragma unroll
  for (int m = 0; m < 8; ++m)
#pragma unroll
    for (int n = 0; n < 2; ++n) acc[m][n] = (f32x4)0.0f;

  s16x8 qfA[2], qfB[2];

  // prologue: B(0), A(0), B(1) — issue order pinned for vmcnt FIFO counting
  gll16(smem.B[0] + (wid << 10), bSeg);
  gll16(smem.B[0] + (wid << 10) + 512, bSeg + (size_t)16 * D_N);
  __builtin_amdgcn_sched_barrier(0);
  qfA[0] = *(const s16x8*)(aReg0);
  qfA[1] = *(const s16x8*)(aReg1);
  __builtin_amdgcn_sched_barrier(0);
  gll16(smem.B[1] + (wid << 10), bSeg + 32);
  gll16(smem.B[1] + (wid << 10) + 512, bSeg + (size_t)16 * D_N + 32);
  __builtin_amdgcn_sched_barrier(0);

#define FOLD(V)                                                               \
  {                                                                           \
    const int kb0 = segBase + (((V) >> 5) << 7) + (g << 2);                   \
    _Pragma("unroll")                                                         \
    for (int n = 0; n < 2; ++n)                                               \
      _Pragma("unroll")                                                       \
      for (int m = 0; m < 8; ++m)                                             \
        _Pragma("unroll")                                                     \
        for (int j = 0; j < 4; ++j) {                                         \
          float val = acc[m][n][j];                                           \
          acc[m][n][j] = 0.0f;                                                \
          int id = kb0 + (m << 4) + j;                                        \
          if (better(val, id, lv[n][TOPK - 1], li[n][TOPK - 1])) {            \
            float cv = val; int ci = id;                                      \
            _Pragma("unroll")                                                 \
            for (int p = 0; p < TOPK; ++p) {                                  \
              if (better(cv, ci, lv[n][p], li[n][p])) {                       \
                float tv = lv[n][p]; int ti = li[n][p];                       \
                lv[n][p] = cv; li[n][p] = ci;                                 \
                cv = tv; ci = ti;                                             \
              }                                                               \
            }                                                                 \
          }                                                                   \
        }                                                                     \
  }

  // step body: PAR = V&1 (compile-time); QCUR used now, QNXT prefetched (V+1)
#define STEP(V, QCUR, QNXT, PAR)                                              \
  {                                                                           \
    if ((V) < NSTEP - 1) {                                                    \
      asm volatile("s_waitcnt vmcnt(2)" ::: "memory");                        \
    } else {                                                                  \
      asm volatile("s_waitcnt vmcnt(0)" ::: "memory");                        \
    }                                                                         \
    __builtin_amdgcn_sched_barrier(0);                                        \
    __builtin_amdgcn_s_barrier();                                             \
    __builtin_amdgcn_sched_barrier(0);                                        \
    const unsigned short* Bb = smem.B[PAR];                                   \
    s16x8 af[8];                                                              \
    _Pragma("unroll")                                                         \
    for (int m = 0; m < 8; ++m) af[m] = *(const s16x8*)(Bb + bBase + (m << 9)); \
    if ((V) + 1 < NSTEP) {                                                    \
      const int kn = ((V) + 1) & 31;                                          \
      QNXT[0] = *(const s16x8*)(aReg0 + (kn << 5));                           \
      QNXT[1] = *(const s16x8*)(aReg1 + (kn << 5));                           \
    }                                                                         \
    asm volatile("s_waitcnt lgkmcnt(0)" ::: "memory");                        \
    __builtin_amdgcn_sched_barrier(0);                                        \
    __builtin_amdgcn_s_barrier();                                             \
    __builtin_amdgcn_sched_barrier(0);                                        \
    if ((V) + 2 < NSTEP) {                                                    \
      const int v2 = (V) + 2;                                                 \
      const unsigned short* bS = bSeg + (size_t)(v2 >> 5) * (128 * D_N) + ((v2 & 31) << 5); \
      gll16(smem.B[PAR] + (wid << 10), bS);                                   \
      gll16(smem.B[PAR] + (wid << 10) + 512, bS + (size_t)16 * D_N);          \
    }                                                                         \
    __builtin_amdgcn_s_setprio(1);                                            \
    _Pragma("unroll")                                                         \
    for (int m = 0; m < 8; ++m) {                                             \
      acc[m][0] = __builtin_amdgcn_mfma_f32_16x16x32_bf16(af[m], QCUR[0], acc[m][0], 0, 0, 0); \
      acc[m][1] = __builtin_amdgcn_mfma_f32_16x16x32_bf16(af[m], QCUR[1], acc[m][1], 0, 0, 0); \
    }                                                                         \
    __builtin_amdgcn_s_setprio(0);                                            \
    if (((V) & (NKT - 1)) == NKT - 1) { FOLD(V); }                            \
  }

#pragma unroll 1
  for (int vb = 0; vb < NSTEP; vb += 2) {
    STEP(vb, qfA, qfB, 0)
    STEP(vb + 1, qfB, qfA, 1)
  }
#undef STEP
#undef FOLD

  __syncthreads();   // all LDS frag reads done before overlaying mg scratch

  // dump per-lane lists: query-local ql = wid*32 + n*16 + fr, group g
#pragma unroll
  for (int n = 0; n < 2; ++n) {
    const int ql = (wid << 5) + (n << 4) + fr;
#pragma unroll
    for (int j = 0; j < TOPK; ++j) {
      smem.mg.v[((ql << 2) + g) * TOPK + j] = lv[n][j];
      smem.mg.i[((ql << 2) + g) * TOPK + j] = li[n][j];
    }
  }
  __syncthreads();

  // thread per query: 4-way merge of the 4 sorted lane-group lists -> top-8
  if (tid < BM) {
    const int rb = tid << 5;   // 4 lists x 8
    int p0 = 0, p1 = 0, p2 = 0, p3 = 0;
    size_t base = (size_t)(qbase + tid) * CANDS + seg * TOPK;
#pragma unroll
    for (int j = 0; j < TOPK; ++j) {
      float v0 = smem.mg.v[rb + 0 + p0];  int i0 = smem.mg.i[rb + 0 + p0];
      float v1 = smem.mg.v[rb + 8 + p1];  int i1 = smem.mg.i[rb + 8 + p1];
      float v2 = smem.mg.v[rb + 16 + p2]; int i2 = smem.mg.i[rb + 16 + p2];
      float v3 = smem.mg.v[rb + 24 + p3]; int i3 = smem.mg.i[rb + 24 + p3];
      float bv = v0; int bi = i0; int sel = 0;
      if (better(v1, i1, bv, bi)) { bv = v1; bi = i1; sel = 1; }
      if (better(v2, i2, bv, bi)) { bv = v2; bi = i2; sel = 2; }
      if (better(v3, i3, bv, bi)) { bv = v3; bi = i3; sel = 3; }
      cand_val[base + j] = bv;
      cand_idx[base + j] = bi;
      p0 += (sel == 0); p1 += (sel == 1); p2 += (sel == 2); p3 += (sel == 3);
    }
  }
}

// ---------------- K4: merge + exact fp32 rescore + select + gather ---------
__global__ __launch_bounds__(256) void merge_kernel(const float* __restrict__ qn,
                                                    const float* __restrict__ keys,
                                                    const float* __restrict__ values,
                                                    const float* __restrict__ rnk,
                                                    const float* __restrict__ cand_val,
                                                    const int* __restrict__ cand_idx,
                                                    float* __restrict__ out) {
  const int q = blockIdx.x;
  const int tid = threadIdx.x;
  const int lane = tid & 63;
  const int w = tid >> 6;
  __shared__ float sv[CANDS];
  __shared__ int si[CANDS];
  sv[tid] = cand_val[(size_t)q * CANDS + tid];
  si[tid] = cand_idx[(size_t)q * CANDS + tid];
  __syncthreads();
  for (int k = 2; k <= CANDS; k <<= 1) {
    for (int j = k >> 1; j > 0; j >>= 1) {
      int ixj = tid ^ j;
      if (ixj > tid) {
        float v0 = sv[tid], v1 = sv[ixj];
        int i0 = si[tid], i1 = si[ixj];
        bool desc = ((tid & k) == 0);
        bool dosw = desc ? better(v1, i1, v0, i0) : better(v0, i0, v1, i1);
        if (dosw) { sv[tid] = v1; si[tid] = i1; sv[ixj] = v0; si[ixj] = i0; }
      }
      __syncthreads();
    }
  }
  __shared__ float rsc[NRES];
  const float* qrow = &qn[(size_t)q * D_N + lane * 16];
  float4 qv0 = *reinterpret_cast<const float4*>(qrow + 0);
  float4 qv1 = *reinterpret_cast<const float4*>(qrow + 4);
  float4 qv2 = *reinterpret_cast<const float4*>(qrow + 8);
  float4 qv3 = *reinterpret_cast<const float4*>(qrow + 12);
  for (int c = w; c < NRES; c += 4) {
    int id = si[c];
    const float* kr = &keys[(size_t)id * D_N + lane * 16];
    float4 k0 = *reinterpret_cast<const float4*>(kr + 0);
    float4 k1 = *reinterpret_cast<const float4*>(kr + 4);
    float4 k2 = *reinterpret_cast<const float4*>(kr + 8);
    float4 k3 = *reinterpret_cast<const float4*>(kr + 12);
    float s = qv0.x * k0.x + qv0.y * k0.y + qv0.z * k0.z + qv0.w * k0.w
            + qv1.x * k1.x + qv1.y * k1.y + qv1.z * k1.z + qv1.w * k1.w
            + qv2.x * k2.x + qv2.y * k2.y + qv2.z * k2.z + qv2.w * k2.w
            + qv3.x * k3.x + qv3.y * k3.y + qv3.z * k3.z + qv3.w * k3.w;
#pragma unroll
    for (int off = 32; off > 0; off >>= 1) s += __shfl_down(s, off);
    if (lane == 0) rsc[c] = s * rnk[id];
  }
  __syncthreads();
  __shared__ int sel[TOPK];
  if (tid == 0) {
    unsigned used = 0;
    for (int j = 0; j < TOPK; ++j) {
      int best = -1;
      for (int c = 0; c < NRES; ++c) {
        if ((used >> c) & 1u) continue;
        if (best < 0 || better(rsc[c], si[c], rsc[best], si[best])) best = c;
      }
      used |= 1u << best;
      sel[j] = si[best];
    }
  }
  __syncthreads();
#pragma unroll
  for (int j = 0; j < TOPK; ++j) {
    int row = sel[j];
    float4 v = *reinterpret_cast<const float4*>(&values[(size_t)row * D_N + tid * 4]);
    *reinterpret_cast<float4*>(&out[(size_t)q * (TOPK * D_N) + j * D_N + tid * 4]) = v;
  }
}

extern "C" void kernel_launch(void* const* d_in, const int* in_sizes, int n_in,
                              void* d_out, int out_size, void* d_ws, size_t ws_size,
                              hipStream_t stream) {
  const float* query  = (const float*)d_in[0];
  const float* keys   = (const float*)d_in[1];
  const float* values = (const float*)d_in[2];
  float* out = (float*)d_out;
  char* ws = (char*)d_ws;

  const size_t offQn  = 0;
  const size_t offQb  = offQn + (size_t)Q_N * D_N * 4;
  const size_t offKb  = offQb + (size_t)Q_N * D_N * 2;
  const size_t offRnk = offKb + (size_t)M_N * D_N * 2;
  const size_t offCv  = offRnk + (size_t)M_N * 4;
  const size_t offCi  = offCv + (size_t)Q_N * CANDS * 4;

  float* qn = (float*)(ws + offQn);
  unsigned short* qb = (unsigned short*)(ws + offQb);
  unsigned short* kb = (unsigned short*)(ws + offKb);
  float* rnk = (float*)(ws + offRnk);
  float* cand_val = (float*)(ws + offCv);
  int* cand_idx = (int*)(ws + offCi);

  hipLaunchKernelGGL(knorm_scale_kernel, dim3(M_N), dim3(256), 0, stream, keys, kb, rnk);
  hipLaunchKernelGGL(qnorm_dual_kernel, dim3(Q_N), dim3(256), 0, stream, query, qn, qb);
  hipLaunchKernelGGL(simsb_kernel, dim3(QT128 * SEGS), dim3(256), 0, stream,
                     qb, kb, cand_val, cand_idx);
  hipLaunchKernelGGL(merge_kernel, dim3(Q_N), dim3(256), 0, stream,
                     qn, keys, values, rnk, cand_val, cand_idx, out);
}

// Round 9
// 1281.604 us; speedup vs baseline: 2.7831x; 1.2208x over previous
//
#include <hip/hip_runtime.h>
#include <hip/hip_bf16.h>
#include <hip/hip_fp16.h>
#include <math.h>

#define Q_N 4096
#define M_N 65536
#define D_N 1024
#define TOPK 8
#define SEGS 32
#define KPS (M_N / SEGS)       // 2048 keys per segment
#define CANDS (SEGS * TOPK)    // 256 candidates per query
#define NRES 32                // rescored candidates per query

// MFMA tile params: 128q x 128k block, BK=64, 4 waves in 2x2 (wave = 64q x 64k)
#define BM 128
#define BN 128
#define BK 64
#define KSPS (D_N / BK)        // 16 K-steps per subtile
#define NSUB (KPS / BN)        // 16 subtiles per segment
#define NSTEPS (NSUB * KSPS)   // 256 pipeline steps per segment
#define QT128 (Q_N / BM)       // 32 query tiles

typedef short s16x8 __attribute__((ext_vector_type(8)));
typedef float f32x4 __attribute__((ext_vector_type(4)));

__device__ __forceinline__ bool better(float v0, int i0, float v1, int i1) {
  return (v0 > v1) || (v0 == v1 && i0 < i1);
}

__device__ __forceinline__ unsigned short f2bf(float f) {
  union { __hip_bfloat16 h; unsigned short u; } c;
  c.h = __float2bfloat16(f);
  return c.u;
}

// async global->LDS, 16B per lane; lds base wave-uniform, dest linear (lane*16)
__device__ __forceinline__ void gll16(void* lds, const void* g) {
  __builtin_amdgcn_global_load_lds(
      (const __attribute__((address_space(1))) unsigned int*)(uintptr_t)g,
      (__attribute__((address_space(3))) unsigned int*)(uintptr_t)lds, 16, 0, 0);
}

// ---------------- K1: key norms + normalized bf16 conversion ----------------
__global__ __launch_bounds__(256) void knorm_scale_kernel(const float* __restrict__ keys,
                                                          unsigned short* __restrict__ kb,
                                                          float* __restrict__ rnk) {
  int row = blockIdx.x;
  int tid = threadIdx.x;
  float4 v = reinterpret_cast<const float4*>(keys + (size_t)row * D_N)[tid];
  float s = v.x * v.x + v.y * v.y + v.z * v.z + v.w * v.w;
#pragma unroll
  for (int off = 32; off > 0; off >>= 1) s += __shfl_down(s, off);
  __shared__ float part[4];
  __shared__ float rs;
  int lane = tid & 63, wid = tid >> 6;
  if (lane == 0) part[wid] = s;
  __syncthreads();
  if (tid == 0) {
    float t = part[0] + part[1] + part[2] + part[3];
    rs = 1.0f / fmaxf(sqrtf(t), 1e-12f);
  }
  __syncthreads();
  float r = rs;
  ushort4 o;
  o.x = f2bf(v.x * r); o.y = f2bf(v.y * r); o.z = f2bf(v.z * r); o.w = f2bf(v.w * r);
  reinterpret_cast<ushort4*>(kb + (size_t)row * D_N)[tid] = o;
  if (tid == 0) rnk[row] = r;
}

// ---------------- K2: query norms -> fp32 (rescore) + bf16 (MFMA) ----------
__global__ __launch_bounds__(256) void qnorm_dual_kernel(const float* __restrict__ q,
                                                         float* __restrict__ qn,
                                                         unsigned short* __restrict__ qb) {
  int row = blockIdx.x;
  int tid = threadIdx.x;
  float4 v = reinterpret_cast<const float4*>(q + (size_t)row * D_N)[tid];
  float s = v.x * v.x + v.y * v.y + v.z * v.z + v.w * v.w;
#pragma unroll
  for (int off = 32; off > 0; off >>= 1) s += __shfl_down(s, off);
  __shared__ float part[4];
  __shared__ float rs;
  int lane = tid & 63, wid = tid >> 6;
  if (lane == 0) part[wid] = s;
  __syncthreads();
  if (tid == 0) {
    float t = part[0] + part[1] + part[2] + part[3];
    rs = 1.0f / fmaxf(sqrtf(t), 1e-12f);
  }
  __syncthreads();
  float r = rs;
  float4 o;
  o.x = v.x * r; o.y = v.y * r; o.z = v.z * r; o.w = v.w * r;
  reinterpret_cast<float4*>(qn + (size_t)row * D_N)[tid] = o;
  ushort4 ob;
  ob.x = f2bf(o.x); ob.y = f2bf(o.y); ob.z = f2bf(o.z); ob.w = f2bf(o.w);
  reinterpret_cast<ushort4*>(qb + (size_t)row * D_N)[tid] = ob;
}

// ---------------- K3: bf16 MFMA sims + in-register per-segment top-8 --------
// R5 skeleton with 2x2 wave grid (wave = 64q x 64k: 32 b128/block-step, -20%)
// and BK=64 (half the barriers/waits per byte). Depth-2 counted-vmcnt pipeline
// (vmcnt(8), never drained mid-loop), raw s_barriers, both operands staged via
// global_load_lds with 3-bit involutive source-side chunk swizzle.
__global__ __launch_bounds__(256, 2) void simsb_kernel(const unsigned short* __restrict__ qb,
                                                       const unsigned short* __restrict__ kb,
                                                       float* __restrict__ cand_val,
                                                       int* __restrict__ cand_idx) {
  __shared__ __align__(16) union SmemU {
    struct {
      unsigned short A[2][BM * BK];  // 2 x 16 KB queries
      unsigned short B[2][BN * BK];  // 2 x 16 KB keys
    } ab;                            // 64 KB
    struct {
      float v[BM * 8 * TOPK];        // 32 KB: per-query 8 lists (2 wr x 4 g)
      int i[BM * 8 * TOPK];          // 32 KB
    } mg;
  } smem;

  const int tid = threadIdx.x;
  const int lane = tid & 63;
  const int wid = tid >> 6;
  const int wr = wid >> 1;           // key half (0,1)
  const int wc = wid & 1;            // query half (0,1)

  // round-synchronized mapping (R5): XCD = orig&7, 4 rounds of 32 CU-slots
  const int orig = blockIdx.x;
  const int seg = (orig & 7) * 4 + (orig >> 8);
  const int qtile = (orig >> 3) & 31;
  const int qbase = qtile * BM;
  const int segBase = seg * KPS;

  // staging: wave wid stages rows [wid*32, +32) of A and of B (4 gll16 each).
  // Per gll16: lane l -> row +(l>>3), phys chunk (l&7) (16B). Source pre-swizzle:
  // logical chunk = (l&7) ^ (l>>3) (involution with row&7).
  const int srow = (wid << 5) + (lane >> 3);
  const int scol = (((lane & 7) ^ (lane >> 3)) << 3);
  const unsigned short* aSrc = qb + (size_t)(qbase + srow) * D_N + scol;
  const unsigned short* bSrc = kb + (size_t)(segBase + srow) * D_N + scol;

  // fragment geometry (16x16x32, swapped operands): fr = lane&15, g = lane>>4
  const int fr = lane & 15;
  const int g = lane >> 4;
  // read offsets (ushort units): row*64 + (((kh<<2)+g) ^ (fr&7))*8
  int aOff[4][2], bOff[4][2];
#pragma unroll
  for (int x = 0; x < 4; ++x)
#pragma unroll
    for (int kh = 0; kh < 2; ++kh) {
      const int chunk = ((kh << 2) + g) ^ (fr & 7);
      aOff[x][kh] = ((wc << 6) + (x << 4) + fr) * 64 + (chunk << 3);
      bOff[x][kh] = ((wr << 6) + (x << 4) + fr) * 64 + (chunk << 3);
    }

  // per-lane running top-8 for 4 queries (q = qbase + wc*64 + n*16 + fr),
  // over this lane's key partition (keys wr*64 + m*16 + g*4 + j)
  float lv[4][TOPK];
  int li[4][TOPK];
#pragma unroll
  for (int n = 0; n < 4; ++n)
#pragma unroll
    for (int j = 0; j < TOPK; ++j) { lv[n][j] = -1e30f; li[n][j] = 0x7fffffff; }

  f32x4 acc[4][4];   // [m key-subtile][n query-subtile]
#pragma unroll
  for (int m = 0; m < 4; ++m)
#pragma unroll
    for (int n = 0; n < 4; ++n) acc[m][n] = (f32x4)0.0f;

  // prologue: stage steps 0,1 (8 gll16/wave each -> 16 outstanding)
#pragma unroll
  for (int p = 0; p < 2; ++p) {
#pragma unroll
    for (int i = 0; i < 4; ++i)
      gll16(smem.ab.A[p] + (wid << 11) + (i << 9), aSrc + (p << 6) + (size_t)(i << 3) * D_N);
#pragma unroll
    for (int i = 0; i < 4; ++i)
      gll16(smem.ab.B[p] + (wid << 11) + (i << 9), bSrc + (p << 6) + (size_t)(i << 3) * D_N);
  }

#pragma unroll 1
  for (int v = 0; v < NSTEPS; ++v) {
    if (v < NSTEPS - 1) {
      asm volatile("s_waitcnt vmcnt(8)" ::: "memory");   // own step's 8 done
    } else {
      asm volatile("s_waitcnt vmcnt(0)" ::: "memory");
    }
    __builtin_amdgcn_sched_barrier(0);
    __builtin_amdgcn_s_barrier();
    __builtin_amdgcn_sched_barrier(0);

    const unsigned short* Ab = smem.ab.A[v & 1];
    const unsigned short* Bb = smem.ab.B[v & 1];
    s16x8 af[4][2], bq[4][2];
#pragma unroll
    for (int x = 0; x < 4; ++x)
#pragma unroll
      for (int kh = 0; kh < 2; ++kh) {
        af[x][kh] = *(const s16x8*)(Bb + bOff[x][kh]);
        bq[x][kh] = *(const s16x8*)(Ab + aOff[x][kh]);
      }
    asm volatile("s_waitcnt lgkmcnt(0)" ::: "memory");
    __builtin_amdgcn_sched_barrier(0);
    __builtin_amdgcn_s_barrier();   // all waves' frag reads done
    __builtin_amdgcn_sched_barrier(0);

    // restage just-read buffer with step v+2 (stays in flight across barriers)
    if (v + 2 < NSTEPS) {
      const int v2 = v + 2;
      const size_t kofs = ((size_t)(v2 >> 4) * 128) * D_N + ((v2 & 15) << 6);
#pragma unroll
      for (int i = 0; i < 4; ++i)
        gll16(smem.ab.A[v & 1] + (wid << 11) + (i << 9),
              aSrc + ((v2 & 15) << 6) + (size_t)(i << 3) * D_N);
#pragma unroll
      for (int i = 0; i < 4; ++i)
        gll16(smem.ab.B[v & 1] + (wid << 11) + (i << 9),
              bSrc + kofs + (size_t)(i << 3) * D_N);
    }

    __builtin_amdgcn_s_setprio(1);
#pragma unroll
    for (int kh = 0; kh < 2; ++kh)
#pragma unroll
      for (int m = 0; m < 4; ++m)
#pragma unroll
        for (int n = 0; n < 4; ++n)
          acc[m][n] = __builtin_amdgcn_mfma_f32_16x16x32_bf16(af[m][kh], bq[n][kh], acc[m][n], 0, 0, 0);
    __builtin_amdgcn_s_setprio(0);

    // subtile boundary (every 16 steps): fold acc into per-lane top-8, reset
    if ((v & (KSPS - 1)) == KSPS - 1) {
      const int kb0 = segBase + ((v >> 4) << 7) + (wr << 6) + (g << 2);
#pragma unroll
      for (int n = 0; n < 4; ++n)
#pragma unroll
        for (int m = 0; m < 4; ++m)
#pragma unroll
          for (int j = 0; j < 4; ++j) {
            float val = acc[m][n][j];
            acc[m][n][j] = 0.0f;
            int id = kb0 + (m << 4) + j;
            if (better(val, id, lv[n][TOPK - 1], li[n][TOPK - 1])) {
              float cv = val; int ci = id;
#pragma unroll
              for (int p = 0; p < TOPK; ++p) {
                if (better(cv, ci, lv[n][p], li[n][p])) {
                  float tv = lv[n][p]; int ti = li[n][p];
                  lv[n][p] = cv; li[n][p] = ci;
                  cv = tv; ci = ti;
                }
              }
            }
          }
    }
  }

  __syncthreads();   // all LDS frag reads done before overlaying mg scratch

  // dump per-lane lists: query-local ql = wc*64 + n*16 + fr, list id = wr*4+g
  {
    const int lid = (wr << 2) + g;
#pragma unroll
    for (int n = 0; n < 4; ++n) {
      const int ql = (wc << 6) + (n << 4) + fr;
#pragma unroll
      for (int j = 0; j < TOPK; ++j) {
        smem.mg.v[((ql << 3) + lid) * TOPK + j] = lv[n][j];
        smem.mg.i[((ql << 3) + lid) * TOPK + j] = li[n][j];
      }
    }
  }
  __syncthreads();

  // thread per query: 8-way merge of the 8 sorted lists -> top-8
  if (tid < BM) {
    const int rb = tid << 6;   // 8 lists x 8
    int p0 = 0, p1 = 0, p2 = 0, p3 = 0, p4 = 0, p5 = 0, p6 = 0, p7 = 0;
    size_t base = (size_t)(qbase + tid) * CANDS + seg * TOPK;
#pragma unroll
    for (int j = 0; j < TOPK; ++j) {
      float bv = smem.mg.v[rb + 0 * 8 + p0];
      int bi = smem.mg.i[rb + 0 * 8 + p0];
      int sel = 0;
#define CHK(L, P)                                                        \
      { float tv = smem.mg.v[rb + (L) * 8 + (P)];                        \
        int ti = smem.mg.i[rb + (L) * 8 + (P)];                          \
        if (better(tv, ti, bv, bi)) { bv = tv; bi = ti; sel = (L); } }
      CHK(1, p1) CHK(2, p2) CHK(3, p3) CHK(4, p4) CHK(5, p5) CHK(6, p6) CHK(7, p7)
#undef CHK
      cand_val[base + j] = bv;
      cand_idx[base + j] = bi;
      p0 += (sel == 0); p1 += (sel == 1); p2 += (sel == 2); p3 += (sel == 3);
      p4 += (sel == 4); p5 += (sel == 5); p6 += (sel == 6); p7 += (sel == 7);
    }
  }
}

// ---------------- K4: merge + exact fp32 rescore + select + gather ---------
__global__ __launch_bounds__(256) void merge_kernel(const float* __restrict__ qn,
                                                    const float* __restrict__ keys,
                                                    const float* __restrict__ values,
                                                    const float* __restrict__ rnk,
                                                    const float* __restrict__ cand_val,
                                                    const int* __restrict__ cand_idx,
                                                    float* __restrict__ out) {
  const int q = blockIdx.x;
  const int tid = threadIdx.x;
  const int lane = tid & 63;
  const int w = tid >> 6;
  __shared__ float sv[CANDS];
  __shared__ int si[CANDS];
  sv[tid] = cand_val[(size_t)q * CANDS + tid];
  si[tid] = cand_idx[(size_t)q * CANDS + tid];
  __syncthreads();
  for (int k = 2; k <= CANDS; k <<= 1) {
    for (int j = k >> 1; j > 0; j >>= 1) {
      int ixj = tid ^ j;
      if (ixj > tid) {
        float v0 = sv[tid], v1 = sv[ixj];
        int i0 = si[tid], i1 = si[ixj];
        bool desc = ((tid & k) == 0);
        bool dosw = desc ? better(v1, i1, v0, i0) : better(v0, i0, v1, i1);
        if (dosw) { sv[tid] = v1; si[tid] = i1; sv[ixj] = v0; si[ixj] = i0; }
      }
      __syncthreads();
    }
  }
  __shared__ float rsc[NRES];
  const float* qrow = &qn[(size_t)q * D_N + lane * 16];
  float4 qv0 = *reinterpret_cast<const float4*>(qrow + 0);
  float4 qv1 = *reinterpret_cast<const float4*>(qrow + 4);
  float4 qv2 = *reinterpret_cast<const float4*>(qrow + 8);
  float4 qv3 = *reinterpret_cast<const float4*>(qrow + 12);
  for (int c = w; c < NRES; c += 4) {
    int id = si[c];
    const float* kr = &keys[(size_t)id * D_N + lane * 16];
    float4 k0 = *reinterpret_cast<const float4*>(kr + 0);
    float4 k1 = *reinterpret_cast<const float4*>(kr + 4);
    float4 k2 = *reinterpret_cast<const float4*>(kr + 8);
    float4 k3 = *reinterpret_cast<const float4*>(kr + 12);
    float s = qv0.x * k0.x + qv0.y * k0.y + qv0.z * k0.z + qv0.w * k0.w
            + qv1.x * k1.x + qv1.y * k1.y + qv1.z * k1.z + qv1.w * k1.w
            + qv2.x * k2.x + qv2.y * k2.y + qv2.z * k2.z + qv2.w * k2.w
            + qv3.x * k3.x + qv3.y * k3.y + qv3.z * k3.z + qv3.w * k3.w;
#pragma unroll
    for (int off = 32; off > 0; off >>= 1) s += __shfl_down(s, off);
    if (lane == 0) rsc[c] = s * rnk[id];
  }
  __syncthreads();
  __shared__ int sel[TOPK];
  if (tid == 0) {
    unsigned used = 0;
    for (int j = 0; j < TOPK; ++j) {
      int best = -1;
      for (int c = 0; c < NRES; ++c) {
        if ((used >> c) & 1u) continue;
        if (best < 0 || better(rsc[c], si[c], rsc[best], si[best])) best = c;
      }
      used |= 1u << best;
      sel[j] = si[best];
    }
  }
  __syncthreads();
#pragma unroll
  for (int j = 0; j < TOPK; ++j) {
    int row = sel[j];
    float4 v = *reinterpret_cast<const float4*>(&values[(size_t)row * D_N + tid * 4]);
    *reinterpret_cast<float4*>(&out[(size_t)q * (TOPK * D_N) + j * D_N + tid * 4]) = v;
  }
}

extern "C" void kernel_launch(void* const* d_in, const int* in_sizes, int n_in,
                              void* d_out, int out_size, void* d_ws, size_t ws_size,
                              hipStream_t stream) {
  const float* query  = (const float*)d_in[0];
  const float* keys   = (const float*)d_in[1];
  const float* values = (const float*)d_in[2];
  float* out = (float*)d_out;
  char* ws = (char*)d_ws;

  const size_t offQn  = 0;
  const size_t offQb  = offQn + (size_t)Q_N * D_N * 4;
  const size_t offKb  = offQb + (size_t)Q_N * D_N * 2;
  const size_t offRnk = offKb + (size_t)M_N * D_N * 2;
  const size_t offCv  = offRnk + (size_t)M_N * 4;
  const size_t offCi  = offCv + (size_t)Q_N * CANDS * 4;

  float* qn = (float*)(ws + offQn);
  unsigned short* qb = (unsigned short*)(ws + offQb);
  unsigned short* kb = (unsigned short*)(ws + offKb);
  float* rnk = (float*)(ws + offRnk);
  float* cand_val = (float*)(ws + offCv);
  int* cand_idx = (int*)(ws + offCi);

  hipLaunchKernelGGL(knorm_scale_kernel, dim3(M_N), dim3(256), 0, stream, keys, kb, rnk);
  hipLaunchKernelGGL(qnorm_dual_kernel, dim3(Q_N), dim3(256), 0, stream, query, qn, qb);
  hipLaunchKernelGGL(simsb_kernel, dim3(QT128 * SEGS), dim3(256), 0, stream,
                     qb, kb, cand_val, cand_idx);
  hipLaunchKernelGGL(merge_kernel, dim3(Q_N), dim3(256), 0, stream,
                     qn, keys, values, rnk, cand_val, cand_idx, out);
}

// Round 10
// 1273.047 us; speedup vs baseline: 2.8018x; 1.0067x over previous
//
#include <hip/hip_runtime.h>
#include <hip/hip_bf16.h>
#include <hip/hip_fp16.h>
#include <math.h>

#define Q_N 4096
#define M_N 65536
#define D_N 1024
#define TOPK 8
#define SEGS 32
#define KPS (M_N / SEGS)       // 2048 keys per segment
#define CANDS (SEGS * TOPK)    // 256 candidates per query
#define NRES 32                // rescored candidates per query

// MFMA tile params (R5-validated skeleton, ring-3 staging)
#define BM 128
#define BN 128
#define BK 32
#define NSUB (KPS / BN)        // 16 subtiles per segment
#define NKT (D_N / BK)         // 32 K-steps per subtile
#define NSTEP (NSUB * NKT)     // 512 pipeline steps per segment
#define QT128 (Q_N / BM)       // 32 query tiles

typedef short s16x8 __attribute__((ext_vector_type(8)));
typedef float f32x4 __attribute__((ext_vector_type(4)));

__device__ __forceinline__ bool better(float v0, int i0, float v1, int i1) {
  return (v0 > v1) || (v0 == v1 && i0 < i1);
}

__device__ __forceinline__ unsigned short f2bf(float f) {
  union { __hip_bfloat16 h; unsigned short u; } c;
  c.h = __float2bfloat16(f);
  return c.u;
}

// async global->LDS, 16B per lane; lds base wave-uniform, dest linear (lane*16)
__device__ __forceinline__ void gll16(void* lds, const void* g) {
  __builtin_amdgcn_global_load_lds(
      (const __attribute__((address_space(1))) unsigned int*)(uintptr_t)g,
      (__attribute__((address_space(3))) unsigned int*)(uintptr_t)lds, 16, 0, 0);
}

// ---------------- K1: key norms + normalized bf16 conversion ----------------
__global__ __launch_bounds__(256) void knorm_scale_kernel(const float* __restrict__ keys,
                                                          unsigned short* __restrict__ kb,
                                                          float* __restrict__ rnk) {
  int row = blockIdx.x;
  int tid = threadIdx.x;
  float4 v = reinterpret_cast<const float4*>(keys + (size_t)row * D_N)[tid];
  float s = v.x * v.x + v.y * v.y + v.z * v.z + v.w * v.w;
#pragma unroll
  for (int off = 32; off > 0; off >>= 1) s += __shfl_down(s, off);
  __shared__ float part[4];
  __shared__ float rs;
  int lane = tid & 63, wid = tid >> 6;
  if (lane == 0) part[wid] = s;
  __syncthreads();
  if (tid == 0) {
    float t = part[0] + part[1] + part[2] + part[3];
    rs = 1.0f / fmaxf(sqrtf(t), 1e-12f);
  }
  __syncthreads();
  float r = rs;
  ushort4 o;
  o.x = f2bf(v.x * r); o.y = f2bf(v.y * r); o.z = f2bf(v.z * r); o.w = f2bf(v.w * r);
  reinterpret_cast<ushort4*>(kb + (size_t)row * D_N)[tid] = o;
  if (tid == 0) rnk[row] = r;
}

// ---------------- K2: query norms -> fp32 (rescore) + bf16 (MFMA) ----------
__global__ __launch_bounds__(256) void qnorm_dual_kernel(const float* __restrict__ q,
                                                         float* __restrict__ qn,
                                                         unsigned short* __restrict__ qb) {
  int row = blockIdx.x;
  int tid = threadIdx.x;
  float4 v = reinterpret_cast<const float4*>(q + (size_t)row * D_N)[tid];
  float s = v.x * v.x + v.y * v.y + v.z * v.z + v.w * v.w;
#pragma unroll
  for (int off = 32; off > 0; off >>= 1) s += __shfl_down(s, off);
  __shared__ float part[4];
  __shared__ float rs;
  int lane = tid & 63, wid = tid >> 6;
  if (lane == 0) part[wid] = s;
  __syncthreads();
  if (tid == 0) {
    float t = part[0] + part[1] + part[2] + part[3];
    rs = 1.0f / fmaxf(sqrtf(t), 1e-12f);
  }
  __syncthreads();
  float r = rs;
  float4 o;
  o.x = v.x * r; o.y = v.y * r; o.z = v.z * r; o.w = v.w * r;
  reinterpret_cast<float4*>(qn + (size_t)row * D_N)[tid] = o;
  ushort4 ob;
  ob.x = f2bf(o.x); ob.y = f2bf(o.y); ob.z = f2bf(o.z); ob.w = f2bf(o.w);
  reinterpret_cast<ushort4*>(qb + (size_t)row * D_N)[tid] = ob;
}

// ---------------- K3: bf16 MFMA sims + in-register per-segment top-8 --------
// R5 skeleton (grid 1024, 4 waves, wave = 32q x 128k, swapped-operand 16x16x32
// MFMA, counted-vmcnt, raw s_barriers) upgraded to a RING-3 LDS staging with
// ONE barrier per step: restage(v+2) targets buf[(v-1)%3], whose readers are
// provably past the step-v barrier (each wave lgkm-drains its v-1 reads before
// reaching it). 48 KB LDS -> 3 blocks/CU (1.5x TLP); restage issued first for
// a full 2-step prefetch lead; vmcnt(4) steady-state, drain 0 only at the end.
__global__ __launch_bounds__(256, 3) void simsb_kernel(const unsigned short* __restrict__ qb,
                                                       const unsigned short* __restrict__ kb,
                                                       float* __restrict__ cand_val,
                                                       int* __restrict__ cand_idx) {
  __shared__ __align__(16) union SmemU {
    struct {
      unsigned short A[3][BM * BK];  // 3 x 8 KB queries
      unsigned short B[3][BN * BK];  // 3 x 8 KB keys
    } ab;                            // 48 KB
    struct {
      float v[BM * 4 * TOPK];        // 16 KB: per-query 4 lane-group lists
      int i[BM * 4 * TOPK];          // 16 KB
    } mg;
  } smem;

  const int tid = threadIdx.x;
  const int lane = tid & 63;
  const int wid = tid >> 6;

  // round-synchronized mapping (R5): XCD = orig&7, 4 rounds of 32 CU-slots
  const int orig = blockIdx.x;
  const int seg = (orig & 7) * 4 + (orig >> 8);
  const int qtile = (orig >> 3) & 31;
  const int qbase = qtile * BM;
  const int segBase = seg * KPS;

  // staging geometry (R5): wave wid stages tile rows [wid*32, wid*32+32)
  // involutive chunk swizzle applied on global source; LDS dest linear
  const int srow = (wid << 5) + (lane >> 2);
  const int scol = (((lane & 3) ^ ((lane >> 3) & 3)) << 3);
  const unsigned short* aSeg = qb + (size_t)(qbase + srow) * D_N + scol;
  const unsigned short* bSeg = kb + (size_t)(segBase + srow) * D_N + scol;

  // fragment geometry (R5): fr = row-within-16, g = k-chunk group
  const int fr = lane & 15;
  const int g = lane >> 4;
  const int chunk_phys = g ^ ((fr >> 1) & 3);
  const int bBase = (fr << 5) + (chunk_phys << 3);                  // keys tile
  const int aBase = (((wid << 5) + fr) << 5) + (chunk_phys << 3);   // query tile

  // per-lane running top-8 for 2 queries (q = qbase + wid*32 + n*16 + fr),
  // over this lane's key partition (keys m*16 + g*4 + j)
  float lv[2][TOPK];
  int li[2][TOPK];
#pragma unroll
  for (int n = 0; n < 2; ++n)
#pragma unroll
    for (int j = 0; j < TOPK; ++j) { lv[n][j] = -1e30f; li[n][j] = 0x7fffffff; }

  f32x4 acc[8][2];
#pragma unroll
  for (int m = 0; m < 8; ++m)
#pragma unroll
    for (int n = 0; n < 2; ++n) acc[m][n] = (f32x4)0.0f;

  // prologue: stage steps 0,1 into ring slots 0,1 (8 loads in flight per wave)
#pragma unroll
  for (int p = 0; p < 2; ++p) {
    const unsigned short* aS = aSeg + (p << 5);
    const unsigned short* bS = bSeg + (p << 5);
    unsigned short* Ad = smem.ab.A[p];
    unsigned short* Bd = smem.ab.B[p];
    gll16(Ad + (wid << 10), aS);
    gll16(Ad + (wid << 10) + 512, aS + (size_t)16 * D_N);
    gll16(Bd + (wid << 10), bS);
    gll16(Bd + (wid << 10) + 512, bS + (size_t)16 * D_N);
  }

  int cur = 0;   // v % 3 ring slot
#pragma unroll 1
  for (int v = 0; v < NSTEP; ++v) {
    // wait for own step's loads (4), leave next step's 4 in flight
    if (v < NSTEP - 1) {
      asm volatile("s_waitcnt vmcnt(4)" ::: "memory");
    } else {
      asm volatile("s_waitcnt vmcnt(0)" ::: "memory");
    }
    __builtin_amdgcn_sched_barrier(0);
    __builtin_amdgcn_s_barrier();   // single barrier per step
    __builtin_amdgcn_sched_barrier(0);

    // restage step v+2 into ring slot (v+2)%3 = (v-1)%3 (readers done: they
    // lgkm-drained their v-1 reads before reaching this step's barrier)
    if (v + 2 < NSTEP) {
      const int v2 = v + 2;
      int nxt = cur + 2; if (nxt >= 3) nxt -= 3;
      const unsigned short* aS = aSeg + ((v2 & 31) << 5);
      const unsigned short* bS = bSeg + ((size_t)(v2 >> 5) * 128) * D_N + ((v2 & 31) << 5);
      unsigned short* Ad = smem.ab.A[nxt];
      unsigned short* Bd = smem.ab.B[nxt];
      gll16(Ad + (wid << 10), aS);
      gll16(Ad + (wid << 10) + 512, aS + (size_t)16 * D_N);
      gll16(Bd + (wid << 10), bS);
      gll16(Bd + (wid << 10) + 512, bS + (size_t)16 * D_N);
    }

    // fragment reads of step v from ring slot cur
    const unsigned short* Ab = smem.ab.A[cur];
    const unsigned short* Bb = smem.ab.B[cur];
    s16x8 af[8], bq[2];
#pragma unroll
    for (int m = 0; m < 8; ++m) af[m] = *(const s16x8*)(Bb + bBase + (m << 9));
#pragma unroll
    for (int n = 0; n < 2; ++n) bq[n] = *(const s16x8*)(Ab + aBase + (n << 9));
    asm volatile("s_waitcnt lgkmcnt(0)" ::: "memory");
    __builtin_amdgcn_sched_barrier(0);

    __builtin_amdgcn_s_setprio(1);
#pragma unroll
    for (int m = 0; m < 8; ++m) {
      acc[m][0] = __builtin_amdgcn_mfma_f32_16x16x32_bf16(af[m], bq[0], acc[m][0], 0, 0, 0);
      acc[m][1] = __builtin_amdgcn_mfma_f32_16x16x32_bf16(af[m], bq[1], acc[m][1], 0, 0, 0);
    }
    __builtin_amdgcn_s_setprio(0);

    // subtile boundary: fold acc into per-lane top-8, reset acc (register-only)
    if ((v & (NKT - 1)) == NKT - 1) {
      const int kb0 = segBase + ((v >> 5) << 7) + (g << 2);
#pragma unroll
      for (int n = 0; n < 2; ++n)
#pragma unroll
        for (int m = 0; m < 8; ++m)
#pragma unroll
          for (int j = 0; j < 4; ++j) {
            float val = acc[m][n][j];
            acc[m][n][j] = 0.0f;
            int id = kb0 + (m << 4) + j;
            if (better(val, id, lv[n][TOPK - 1], li[n][TOPK - 1])) {
              float cv = val; int ci = id;
#pragma unroll
              for (int p = 0; p < TOPK; ++p) {
                if (better(cv, ci, lv[n][p], li[n][p])) {
                  float tv = lv[n][p]; int ti = li[n][p];
                  lv[n][p] = cv; li[n][p] = ci;
                  cv = tv; ci = ti;
                }
              }
            }
          }
    }

    ++cur; if (cur == 3) cur = 0;
  }

  __syncthreads();   // all LDS frag reads done before overlaying mg scratch

  // dump per-lane lists: query-local ql = wid*32 + n*16 + fr, group g
#pragma unroll
  for (int n = 0; n < 2; ++n) {
    const int ql = (wid << 5) + (n << 4) + fr;
#pragma unroll
    for (int j = 0; j < TOPK; ++j) {
      smem.mg.v[((ql << 2) + g) * TOPK + j] = lv[n][j];
      smem.mg.i[((ql << 2) + g) * TOPK + j] = li[n][j];
    }
  }
  __syncthreads();

  // thread per query: 4-way merge of the 4 sorted lane-group lists -> top-8
  if (tid < BM) {
    const int rb = tid << 5;   // 4 lists x 8
    int p0 = 0, p1 = 0, p2 = 0, p3 = 0;
    size_t base = (size_t)(qbase + tid) * CANDS + seg * TOPK;
#pragma unroll
    for (int j = 0; j < TOPK; ++j) {
      float v0 = smem.mg.v[rb + 0 + p0];  int i0 = smem.mg.i[rb + 0 + p0];
      float v1 = smem.mg.v[rb + 8 + p1];  int i1 = smem.mg.i[rb + 8 + p1];
      float v2 = smem.mg.v[rb + 16 + p2]; int i2 = smem.mg.i[rb + 16 + p2];
      float v3 = smem.mg.v[rb + 24 + p3]; int i3 = smem.mg.i[rb + 24 + p3];
      float bv = v0; int bi = i0; int sel = 0;
      if (better(v1, i1, bv, bi)) { bv = v1; bi = i1; sel = 1; }
      if (better(v2, i2, bv, bi)) { bv = v2; bi = i2; sel = 2; }
      if (better(v3, i3, bv, bi)) { bv = v3; bi = i3; sel = 3; }
      cand_val[base + j] = bv;
      cand_idx[base + j] = bi;
      p0 += (sel == 0); p1 += (sel == 1); p2 += (sel == 2); p3 += (sel == 3);
    }
  }
}

// ---------------- K4: merge + exact fp32 rescore + select + gather ---------
__global__ __launch_bounds__(256) void merge_kernel(const float* __restrict__ qn,
                                                    const float* __restrict__ keys,
                                                    const float* __restrict__ values,
                                                    const float* __restrict__ rnk,
                                                    const float* __restrict__ cand_val,
                                                    const int* __restrict__ cand_idx,
                                                    float* __restrict__ out) {
  const int q = blockIdx.x;
  const int tid = threadIdx.x;
  const int lane = tid & 63;
  const int w = tid >> 6;
  __shared__ float sv[CANDS];
  __shared__ int si[CANDS];
  sv[tid] = cand_val[(size_t)q * CANDS + tid];
  si[tid] = cand_idx[(size_t)q * CANDS + tid];
  __syncthreads();
  for (int k = 2; k <= CANDS; k <<= 1) {
    for (int j = k >> 1; j > 0; j >>= 1) {
      int ixj = tid ^ j;
      if (ixj > tid) {
        float v0 = sv[tid], v1 = sv[ixj];
        int i0 = si[tid], i1 = si[ixj];
        bool desc = ((tid & k) == 0);
        bool dosw = desc ? better(v1, i1, v0, i0) : better(v0, i0, v1, i1);
        if (dosw) { sv[tid] = v1; si[tid] = i1; sv[ixj] = v0; si[ixj] = i0; }
      }
      __syncthreads();
    }
  }
  __shared__ float rsc[NRES];
  const float* qrow = &qn[(size_t)q * D_N + lane * 16];
  float4 qv0 = *reinterpret_cast<const float4*>(qrow + 0);
  float4 qv1 = *reinterpret_cast<const float4*>(qrow + 4);
  float4 qv2 = *reinterpret_cast<const float4*>(qrow + 8);
  float4 qv3 = *reinterpret_cast<const float4*>(qrow + 12);
  for (int c = w; c < NRES; c += 4) {
    int id = si[c];
    const float* kr = &keys[(size_t)id * D_N + lane * 16];
    float4 k0 = *reinterpret_cast<const float4*>(kr + 0);
    float4 k1 = *reinterpret_cast<const float4*>(kr + 4);
    float4 k2 = *reinterpret_cast<const float4*>(kr + 8);
    float4 k3 = *reinterpret_cast<const float4*>(kr + 12);
    float s = qv0.x * k0.x + qv0.y * k0.y + qv0.z * k0.z + qv0.w * k0.w
            + qv1.x * k1.x + qv1.y * k1.y + qv1.z * k1.z + qv1.w * k1.w
            + qv2.x * k2.x + qv2.y * k2.y + qv2.z * k2.z + qv2.w * k2.w
            + qv3.x * k3.x + qv3.y * k3.y + qv3.z * k3.z + qv3.w * k3.w;
#pragma unroll
    for (int off = 32; off > 0; off >>= 1) s += __shfl_down(s, off);
    if (lane == 0) rsc[c] = s * rnk[id];
  }
  __syncthreads();
  __shared__ int sel[TOPK];
  if (tid == 0) {
    unsigned used = 0;
    for (int j = 0; j < TOPK; ++j) {
      int best = -1;
      for (int c = 0; c < NRES; ++c) {
        if ((used >> c) & 1u) continue;
        if (best < 0 || better(rsc[c], si[c], rsc[best], si[best])) best = c;
      }
      used |= 1u << best;
      sel[j] = si[best];
    }
  }
  __syncthreads();
#pragma unroll
  for (int j = 0; j < TOPK; ++j) {
    int row = sel[j];
    float4 v = *reinterpret_cast<const float4*>(&values[(size_t)row * D_N + tid * 4]);
    *reinterpret_cast<float4*>(&out[(size_t)q * (TOPK * D_N) + j * D_N + tid * 4]) = v;
  }
}

extern "C" void kernel_launch(void* const* d_in, const int* in_sizes, int n_in,
                              void* d_out, int out_size, void* d_ws, size_t ws_size,
                              hipStream_t stream) {
  const float* query  = (const float*)d_in[0];
  const float* keys   = (const float*)d_in[1];
  const float* values = (const float*)d_in[2];
  float* out = (float*)d_out;
  char* ws = (char*)d_ws;

  const size_t offQn  = 0;
  const size_t offQb  = offQn + (size_t)Q_N * D_N * 4;
  const size_t offKb  = offQb + (size_t)Q_N * D_N * 2;
  const size_t offRnk = offKb + (size_t)M_N * D_N * 2;
  const size_t offCv  = offRnk + (size_t)M_N * 4;
  const size_t offCi  = offCv + (size_t)Q_N * CANDS * 4;

  float* qn = (float*)(ws + offQn);
  unsigned short* qb = (unsigned short*)(ws + offQb);
  unsigned short* kb = (unsigned short*)(ws + offKb);
  float* rnk = (float*)(ws + offRnk);
  float* cand_val = (float*)(ws + offCv);
  int* cand_idx = (int*)(ws + offCi);

  hipLaunchKernelGGL(knorm_scale_kernel, dim3(M_N), dim3(256), 0, stream, keys, kb, rnk);
  hipLaunchKernelGGL(qnorm_dual_kernel, dim3(Q_N), dim3(256), 0, stream, query, qn, qb);
  hipLaunchKernelGGL(simsb_kernel, dim3(QT128 * SEGS), dim3(256), 0, stream,
                     qb, kb, cand_val, cand_idx);
  hipLaunchKernelGGL(merge_kernel, dim3(Q_N), dim3(256), 0, stream,
                     qn, keys, values, rnk, cand_val, cand_idx, out);
}

// Round 11
// 1236.046 us; speedup vs baseline: 2.8856x; 1.0299x over previous
//
#include <hip/hip_runtime.h>
#include <hip/hip_bf16.h>
#include <hip/hip_fp16.h>
#include <math.h>

#define Q_N 4096
#define M_N 65536
#define D_N 1024
#define TOPK 8
#define SEGS 32
#define KPS (M_N / SEGS)       // 2048 keys per segment
#define CANDS (SEGS * TOPK)    // 256 candidates per query
#define NRES 32                // rescored candidates per query

// MFMA tile params (R5-validated skeleton, ring-3 staging)
#define BM 128
#define BN 128
#define BK 32
#define NSUB (KPS / BN)        // 16 subtiles per segment
#define NKT (D_N / BK)         // 32 K-steps per subtile
#define NSTEP (NSUB * NKT)     // 512 pipeline steps per segment
#define QT128 (Q_N / BM)       // 32 query tiles

typedef short s16x8 __attribute__((ext_vector_type(8)));
typedef float f32x4 __attribute__((ext_vector_type(4)));

__device__ __forceinline__ bool better(float v0, int i0, float v1, int i1) {
  return (v0 > v1) || (v0 == v1 && i0 < i1);
}

__device__ __forceinline__ unsigned short f2bf(float f) {
  union { __hip_bfloat16 h; unsigned short u; } c;
  c.h = __float2bfloat16(f);
  return c.u;
}

// async global->LDS, 16B per lane; lds base wave-uniform, dest linear (lane*16)
__device__ __forceinline__ void gll16(void* lds, const void* g) {
  __builtin_amdgcn_global_load_lds(
      (const __attribute__((address_space(1))) unsigned int*)(uintptr_t)g,
      (__attribute__((address_space(3))) unsigned int*)(uintptr_t)lds, 16, 0, 0);
}

// ---------------- K1: key norms + normalized bf16 conversion ----------------
__global__ __launch_bounds__(256) void knorm_scale_kernel(const float* __restrict__ keys,
                                                          unsigned short* __restrict__ kb,
                                                          float* __restrict__ rnk) {
  int row = blockIdx.x;
  int tid = threadIdx.x;
  float4 v = reinterpret_cast<const float4*>(keys + (size_t)row * D_N)[tid];
  float s = v.x * v.x + v.y * v.y + v.z * v.z + v.w * v.w;
#pragma unroll
  for (int off = 32; off > 0; off >>= 1) s += __shfl_down(s, off);
  __shared__ float part[4];
  __shared__ float rs;
  int lane = tid & 63, wid = tid >> 6;
  if (lane == 0) part[wid] = s;
  __syncthreads();
  if (tid == 0) {
    float t = part[0] + part[1] + part[2] + part[3];
    rs = 1.0f / fmaxf(sqrtf(t), 1e-12f);
  }
  __syncthreads();
  float r = rs;
  ushort4 o;
  o.x = f2bf(v.x * r); o.y = f2bf(v.y * r); o.z = f2bf(v.z * r); o.w = f2bf(v.w * r);
  reinterpret_cast<ushort4*>(kb + (size_t)row * D_N)[tid] = o;
  if (tid == 0) rnk[row] = r;
}

// ---------------- K2: query norms -> fp32 (rescore) + bf16 (MFMA) ----------
__global__ __launch_bounds__(256) void qnorm_dual_kernel(const float* __restrict__ q,
                                                         float* __restrict__ qn,
                                                         unsigned short* __restrict__ qb) {
  int row = blockIdx.x;
  int tid = threadIdx.x;
  float4 v = reinterpret_cast<const float4*>(q + (size_t)row * D_N)[tid];
  float s = v.x * v.x + v.y * v.y + v.z * v.z + v.w * v.w;
#pragma unroll
  for (int off = 32; off > 0; off >>= 1) s += __shfl_down(s, off);
  __shared__ float part[4];
  __shared__ float rs;
  int lane = tid & 63, wid = tid >> 6;
  if (lane == 0) part[wid] = s;
  __syncthreads();
  if (tid == 0) {
    float t = part[0] + part[1] + part[2] + part[3];
    rs = 1.0f / fmaxf(sqrtf(t), 1e-12f);
  }
  __syncthreads();
  float r = rs;
  float4 o;
  o.x = v.x * r; o.y = v.y * r; o.z = v.z * r; o.w = v.w * r;
  reinterpret_cast<float4*>(qn + (size_t)row * D_N)[tid] = o;
  ushort4 ob;
  ob.x = f2bf(o.x); ob.y = f2bf(o.y); ob.z = f2bf(o.z); ob.w = f2bf(o.w);
  reinterpret_cast<ushort4*>(qb + (size_t)row * D_N)[tid] = ob;
}

// ---------------- K3: bf16 MFMA sims + in-register per-segment top-8 --------
// R10 skeleton (ring-3 LDS staging, ONE barrier/step, counted vmcnt(4), raw
// s_barriers, swapped-operand 16x16x32 MFMA, in-register top-8) with a
// CACHE-PARTITIONED mapping: XCD pair p = x>>1 owns qtiles 8p..8p+7; x&1
// selects segs 0-15 vs 16-31. Per XCD: A-slice = 8 qtiles x 256KB = 2MB ->
// L2-resident (A-fills ~0); key panels shared 8-way by co-round blocks.
__global__ __launch_bounds__(256, 3) void simsb_kernel(const unsigned short* __restrict__ qb,
                                                       const unsigned short* __restrict__ kb,
                                                       float* __restrict__ cand_val,
                                                       int* __restrict__ cand_idx) {
  __shared__ __align__(16) union SmemU {
    struct {
      unsigned short A[3][BM * BK];  // 3 x 8 KB queries
      unsigned short B[3][BN * BK];  // 3 x 8 KB keys
    } ab;                            // 48 KB
    struct {
      float v[BM * 4 * TOPK];        // 16 KB: per-query 4 lane-group lists
      int i[BM * 4 * TOPK];          // 16 KB
    } mg;
  } smem;

  const int tid = threadIdx.x;
  const int lane = tid & 63;
  const int wid = tid >> 6;

  // cache-partitioned mapping: x = XCD (round-robin dispatch), idx in-XCD.
  // qtile = (x>>1)*8 + (idx&7)  (8 qtiles per XCD pair -> 2MB A-slice per XCD)
  // seg   = (x&1)*16 + (idx>>3) (16 segs per XCD; bijective over qtile x seg)
  const int orig = blockIdx.x;
  const int x = orig & 7;
  const int idx = orig >> 3;
  const int qtile = ((x >> 1) << 3) + (idx & 7);
  const int seg = ((x & 1) << 4) + (idx >> 3);
  const int qbase = qtile * BM;
  const int segBase = seg * KPS;

  // staging geometry (R5): wave wid stages tile rows [wid*32, wid*32+32)
  // involutive chunk swizzle applied on global source; LDS dest linear
  const int srow = (wid << 5) + (lane >> 2);
  const int scol = (((lane & 3) ^ ((lane >> 3) & 3)) << 3);
  const unsigned short* aSeg = qb + (size_t)(qbase + srow) * D_N + scol;
  const unsigned short* bSeg = kb + (size_t)(segBase + srow) * D_N + scol;

  // fragment geometry (R5): fr = row-within-16, g = k-chunk group
  const int fr = lane & 15;
  const int g = lane >> 4;
  const int chunk_phys = g ^ ((fr >> 1) & 3);
  const int bBase = (fr << 5) + (chunk_phys << 3);                  // keys tile
  const int aBase = (((wid << 5) + fr) << 5) + (chunk_phys << 3);   // query tile

  // per-lane running top-8 for 2 queries (q = qbase + wid*32 + n*16 + fr),
  // over this lane's key partition (keys m*16 + g*4 + j)
  float lv[2][TOPK];
  int li[2][TOPK];
#pragma unroll
  for (int n = 0; n < 2; ++n)
#pragma unroll
    for (int j = 0; j < TOPK; ++j) { lv[n][j] = -1e30f; li[n][j] = 0x7fffffff; }

  f32x4 acc[8][2];
#pragma unroll
  for (int m = 0; m < 8; ++m)
#pragma unroll
    for (int n = 0; n < 2; ++n) acc[m][n] = (f32x4)0.0f;

  // prologue: stage steps 0,1 into ring slots 0,1 (8 loads in flight per wave)
#pragma unroll
  for (int p = 0; p < 2; ++p) {
    const unsigned short* aS = aSeg + (p << 5);
    const unsigned short* bS = bSeg + (p << 5);
    unsigned short* Ad = smem.ab.A[p];
    unsigned short* Bd = smem.ab.B[p];
    gll16(Ad + (wid << 10), aS);
    gll16(Ad + (wid << 10) + 512, aS + (size_t)16 * D_N);
    gll16(Bd + (wid << 10), bS);
    gll16(Bd + (wid << 10) + 512, bS + (size_t)16 * D_N);
  }

  int cur = 0;   // v % 3 ring slot
#pragma unroll 1
  for (int v = 0; v < NSTEP; ++v) {
    // wait for own step's loads (4), leave next step's 4 in flight
    if (v < NSTEP - 1) {
      asm volatile("s_waitcnt vmcnt(4)" ::: "memory");
    } else {
      asm volatile("s_waitcnt vmcnt(0)" ::: "memory");
    }
    __builtin_amdgcn_sched_barrier(0);
    __builtin_amdgcn_s_barrier();   // single barrier per step
    __builtin_amdgcn_sched_barrier(0);

    // restage step v+2 into ring slot (v+2)%3 = (v-1)%3 (readers done: they
    // lgkm-drained their v-1 reads before reaching this step's barrier)
    if (v + 2 < NSTEP) {
      const int v2 = v + 2;
      int nxt = cur + 2; if (nxt >= 3) nxt -= 3;
      const unsigned short* aS = aSeg + ((v2 & 31) << 5);
      const unsigned short* bS = bSeg + ((size_t)(v2 >> 5) * 128) * D_N + ((v2 & 31) << 5);
      unsigned short* Ad = smem.ab.A[nxt];
      unsigned short* Bd = smem.ab.B[nxt];
      gll16(Ad + (wid << 10), aS);
      gll16(Ad + (wid << 10) + 512, aS + (size_t)16 * D_N);
      gll16(Bd + (wid << 10), bS);
      gll16(Bd + (wid << 10) + 512, bS + (size_t)16 * D_N);
    }

    // fragment reads of step v from ring slot cur
    const unsigned short* Ab = smem.ab.A[cur];
    const unsigned short* Bb = smem.ab.B[cur];
    s16x8 af[8], bq[2];
#pragma unroll
    for (int m = 0; m < 8; ++m) af[m] = *(const s16x8*)(Bb + bBase + (m << 9));
#pragma unroll
    for (int n = 0; n < 2; ++n) bq[n] = *(const s16x8*)(Ab + aBase + (n << 9));
    asm volatile("s_waitcnt lgkmcnt(0)" ::: "memory");
    __builtin_amdgcn_sched_barrier(0);

    __builtin_amdgcn_s_setprio(1);
#pragma unroll
    for (int m = 0; m < 8; ++m) {
      acc[m][0] = __builtin_amdgcn_mfma_f32_16x16x32_bf16(af[m], bq[0], acc[m][0], 0, 0, 0);
      acc[m][1] = __builtin_amdgcn_mfma_f32_16x16x32_bf16(af[m], bq[1], acc[m][1], 0, 0, 0);
    }
    __builtin_amdgcn_s_setprio(0);

    // subtile boundary: fold acc into per-lane top-8, reset acc (register-only)
    if ((v & (NKT - 1)) == NKT - 1) {
      const int kb0 = segBase + ((v >> 5) << 7) + (g << 2);
#pragma unroll
      for (int n = 0; n < 2; ++n)
#pragma unroll
        for (int m = 0; m < 8; ++m)
#pragma unroll
          for (int j = 0; j < 4; ++j) {
            float val = acc[m][n][j];
            acc[m][n][j] = 0.0f;
            int id = kb0 + (m << 4) + j;
            if (better(val, id, lv[n][TOPK - 1], li[n][TOPK - 1])) {
              float cv = val; int ci = id;
#pragma unroll
              for (int p = 0; p < TOPK; ++p) {
                if (better(cv, ci, lv[n][p], li[n][p])) {
                  float tv = lv[n][p]; int ti = li[n][p];
                  lv[n][p] = cv; li[n][p] = ci;
                  cv = tv; ci = ti;
                }
              }
            }
          }
    }

    ++cur; if (cur == 3) cur = 0;
  }

  __syncthreads();   // all LDS frag reads done before overlaying mg scratch

  // dump per-lane lists: query-local ql = wid*32 + n*16 + fr, group g
#pragma unroll
  for (int n = 0; n < 2; ++n) {
    const int ql = (wid << 5) + (n << 4) + fr;
#pragma unroll
    for (int j = 0; j < TOPK; ++j) {
      smem.mg.v[((ql << 2) + g) * TOPK + j] = lv[n][j];
      smem.mg.i[((ql << 2) + g) * TOPK + j] = li[n][j];
    }
  }
  __syncthreads();

  // thread per query: 4-way merge of the 4 sorted lane-group lists -> top-8
  if (tid < BM) {
    const int rb = tid << 5;   // 4 lists x 8
    int p0 = 0, p1 = 0, p2 = 0, p3 = 0;
    size_t base = (size_t)(qbase + tid) * CANDS + seg * TOPK;
#pragma unroll
    for (int j = 0; j < TOPK; ++j) {
      float v0 = smem.mg.v[rb + 0 + p0];  int i0 = smem.mg.i[rb + 0 + p0];
      float v1 = smem.mg.v[rb + 8 + p1];  int i1 = smem.mg.i[rb + 8 + p1];
      float v2 = smem.mg.v[rb + 16 + p2]; int i2 = smem.mg.i[rb + 16 + p2];
      float v3 = smem.mg.v[rb + 24 + p3]; int i3 = smem.mg.i[rb + 24 + p3];
      float bv = v0; int bi = i0; int sel = 0;
      if (better(v1, i1, bv, bi)) { bv = v1; bi = i1; sel = 1; }
      if (better(v2, i2, bv, bi)) { bv = v2; bi = i2; sel = 2; }
      if (better(v3, i3, bv, bi)) { bv = v3; bi = i3; sel = 3; }
      cand_val[base + j] = bv;
      cand_idx[base + j] = bi;
      p0 += (sel == 0); p1 += (sel == 1); p2 += (sel == 2); p3 += (sel == 3);
    }
  }
}

// ---------------- K4: merge + exact fp32 rescore + select + gather ---------
__global__ __launch_bounds__(256) void merge_kernel(const float* __restrict__ qn,
                                                    const float* __restrict__ keys,
                                                    const float* __restrict__ values,
                                                    const float* __restrict__ rnk,
                                                    const float* __restrict__ cand_val,
                                                    const int* __restrict__ cand_idx,
                                                    float* __restrict__ out) {
  const int q = blockIdx.x;
  const int tid = threadIdx.x;
  const int lane = tid & 63;
  const int w = tid >> 6;
  __shared__ float sv[CANDS];
  __shared__ int si[CANDS];
  sv[tid] = cand_val[(size_t)q * CANDS + tid];
  si[tid] = cand_idx[(size_t)q * CANDS + tid];
  __syncthreads();
  for (int k = 2; k <= CANDS; k <<= 1) {
    for (int j = k >> 1; j > 0; j >>= 1) {
      int ixj = tid ^ j;
      if (ixj > tid) {
        float v0 = sv[tid], v1 = sv[ixj];
        int i0 = si[tid], i1 = si[ixj];
        bool desc = ((tid & k) == 0);
        bool dosw = desc ? better(v1, i1, v0, i0) : better(v0, i0, v1, i1);
        if (dosw) { sv[tid] = v1; si[tid] = i1; sv[ixj] = v0; si[ixj] = i0; }
      }
      __syncthreads();
    }
  }
  __shared__ float rsc[NRES];
  const float* qrow = &qn[(size_t)q * D_N + lane * 16];
  float4 qv0 = *reinterpret_cast<const float4*>(qrow + 0);
  float4 qv1 = *reinterpret_cast<const float4*>(qrow + 4);
  float4 qv2 = *reinterpret_cast<const float4*>(qrow + 8);
  float4 qv3 = *reinterpret_cast<const float4*>(qrow + 12);
  for (int c = w; c < NRES; c += 4) {
    int id = si[c];
    const float* kr = &keys[(size_t)id * D_N + lane * 16];
    float4 k0 = *reinterpret_cast<const float4*>(kr + 0);
    float4 k1 = *reinterpret_cast<const float4*>(kr + 4);
    float4 k2 = *reinterpret_cast<const float4*>(kr + 8);
    float4 k3 = *reinterpret_cast<const float4*>(kr + 12);
    float s = qv0.x * k0.x + qv0.y * k0.y + qv0.z * k0.z + qv0.w * k0.w
            + qv1.x * k1.x + qv1.y * k1.y + qv1.z * k1.z + qv1.w * k1.w
            + qv2.x * k2.x + qv2.y * k2.y + qv2.z * k2.z + qv2.w * k2.w
            + qv3.x * k3.x + qv3.y * k3.y + qv3.z * k3.z + qv3.w * k3.w;
#pragma unroll
    for (int off = 32; off > 0; off >>= 1) s += __shfl_down(s, off);
    if (lane == 0) rsc[c] = s * rnk[id];
  }
  __syncthreads();
  __shared__ int sel[TOPK];
  if (tid == 0) {
    unsigned used = 0;
    for (int j = 0; j < TOPK; ++j) {
      int best = -1;
      for (int c = 0; c < NRES; ++c) {
        if ((used >> c) & 1u) continue;
        if (best < 0 || better(rsc[c], si[c], rsc[best], si[best])) best = c;
      }
      used |= 1u << best;
      sel[j] = si[best];
    }
  }
  __syncthreads();
#pragma unroll
  for (int j = 0; j < TOPK; ++j) {
    int row = sel[j];
    float4 v = *reinterpret_cast<const float4*>(&values[(size_t)row * D_N + tid * 4]);
    *reinterpret_cast<float4*>(&out[(size_t)q * (TOPK * D_N) + j * D_N + tid * 4]) = v;
  }
}

extern "C" void kernel_launch(void* const* d_in, const int* in_sizes, int n_in,
                              void* d_out, int out_size, void* d_ws, size_t ws_size,
                              hipStream_t stream) {
  const float* query  = (const float*)d_in[0];
  const float* keys   = (const float*)d_in[1];
  const float* values = (const float*)d_in[2];
  float* out = (float*)d_out;
  char* ws = (char*)d_ws;

  const size_t offQn  = 0;
  const size_t offQb  = offQn + (size_t)Q_N * D_N * 4;
  const size_t offKb  = offQb + (size_t)Q_N * D_N * 2;
  const size_t offRnk = offKb + (size_t)M_N * D_N * 2;
  const size_t offCv  = offRnk + (size_t)M_N * 4;
  const size_t offCi  = offCv + (size_t)Q_N * CANDS * 4;

  float* qn = (float*)(ws + offQn);
  unsigned short* qb = (unsigned short*)(ws + offQb);
  unsigned short* kb = (unsigned short*)(ws + offKb);
  float* rnk = (float*)(ws + offRnk);
  float* cand_val = (float*)(ws + offCv);
  int* cand_idx = (int*)(ws + offCi);

  hipLaunchKernelGGL(knorm_scale_kernel, dim3(M_N), dim3(256), 0, stream, keys, kb, rnk);
  hipLaunchKernelGGL(qnorm_dual_kernel, dim3(Q_N), dim3(256), 0, stream, query, qn, qb);
  hipLaunchKernelGGL(simsb_kernel, dim3(QT128 * SEGS), dim3(256), 0, stream,
                     qb, kb, cand_val, cand_idx);
  hipLaunchKernelGGL(merge_kernel, dim3(Q_N), dim3(256), 0, stream,
                     qn, keys, values, rnk, cand_val, cand_idx, out);
}